// Round 13
// baseline (464.114 us; speedup 1.0000x reference)
//
#include <hip/hip_runtime.h>
#include <hip/hip_bf16.h>

// SR-GNN session model, MI355X (gfx950). Inputs fp32/int32, output fp32.
// r13: score GEMM moved to MFMA (bf16). 13.1 GFLOP fp32-VALU had an 83us
// hard floor (r12's score5 ~260us at 2 waves/SIMD); bf16 MFMA needs ~5us of
// matrix pipe -> score becomes write-bound (~130us for 819MB).
// Precision: sg split hi+lo (2 MFMAs, sg rounding eliminated); emb single
// bf16 (worst-case +0.02 on top of 0.031; threshold 0.149).
// Fragment mapping reused from r1 (r1 MFMA == r2 fp32 byte-identical errors
// under the packed-bf16 output bug -> mapping verified correct).
// session3 (r10) verbatim.
//
// ws: [0) sg f32 512KB | [512K) sg_hi 256KB | [768K) sg_lo 256KB
//     [1M) emb_b bf16 EMB_ROWS x 32 (3.07MB)   total ~4.1MB (<6.94MB proven)

#define B_BATCH 4096
#define N_NODE  16
#define L_SEQ   20
#define D_DIM   32
#define NV_OUT  49999
#define EMB_ROWS 50176   // 196*256: last tile reach

typedef float  f32x4  __attribute__((ext_vector_type(4)));
typedef __bf16 bf16x8 __attribute__((ext_vector_type(8)));

__device__ __forceinline__ float sigf(float x) {
    return 1.0f / (1.0f + __expf(-x));
}

// ---------------------------------------------------------------- kernel 1
// VERBATIM r10 session3: one block per session; 8 node-groups x 32 d-lanes.
__global__ __launch_bounds__(256) void session3_kernel(
    const int*   __restrict__ alias_inputs,  // [B,20]
    const float* __restrict__ A,             // [B,16,32]
    const int*   __restrict__ items,         // [B,16]
    const int*   __restrict__ mask,          // [B,20]
    const float* __restrict__ emb,           // [V,32]
    const float* __restrict__ w_ih,          // [96,64]
    const float* __restrict__ w_hh,          // [96,32]
    const float* __restrict__ b_ih, const float* __restrict__ b_hh,
    const float* __restrict__ b_iah, const float* __restrict__ b_oah,
    const float* __restrict__ w_ein, const float* __restrict__ b_ein,
    const float* __restrict__ w_eout, const float* __restrict__ b_eout,
    const float* __restrict__ w1, const float* __restrict__ b1,
    const float* __restrict__ w2, const float* __restrict__ b2,
    const float* __restrict__ w3,
    float* __restrict__ sg_out)              // [B,32] fp32 (ws)
{
    const int b   = blockIdx.x;
    const int tid = threadIdx.x;
    const int g   = tid >> 5;
    const int d   = tid & 31;
    const int n0  = g, n1 = g + 8;

    __shared__ float h_s [N_NODE][D_DIM];
    __shared__ float A_s [N_NODE][2 * N_NODE];
    __shared__ float ni_s[N_NODE][D_DIM];
    __shared__ float no_s[N_NODE][D_DIM];
    __shared__ float ii_s[N_NODE][D_DIM];
    __shared__ float io_s[N_NODE][D_DIM];
    __shared__ float wih_s[96][66];           // bank=(2d+k)%32 -> 2-way (free)
    __shared__ float whh_s[96][34];
    __shared__ float q1_s[D_DIM];
    __shared__ float alpha_s[L_SEQ];
    __shared__ int   last_s;

    for (int idx = tid; idx < 512; idx += 256) {
        const int n = idx >> 5, dd = idx & 31;
        const int it = items[b * N_NODE + n];
        h_s[n][dd] = emb[(size_t)it * D_DIM + dd];
        A_s[n][dd] = A[(size_t)b * 512 + idx];
    }
    for (int f = tid; f < 96 * 64; f += 256) wih_s[f >> 6][f & 63] = w_ih[f];
    for (int f = tid; f < 96 * 32; f += 256) whh_s[f >> 5][f & 31] = w_hh[f];
    __syncthreads();

    float ai0 = b_ein[d], ao0 = b_eout[d];
    float ai1 = ai0,      ao1 = ao0;
    #pragma unroll
    for (int k = 0; k < 32; ++k) {
        const float we = w_ein[k * 32 + d], wo = w_eout[k * 32 + d];
        const float h0 = h_s[n0][k], h1 = h_s[n1][k];
        ai0 += h0 * we; ai1 += h1 * we;
        ao0 += h0 * wo; ao1 += h1 * wo;
    }
    ni_s[n0][d] = ai0; ni_s[n1][d] = ai1;
    no_s[n0][d] = ao0; no_s[n1][d] = ao1;
    __syncthreads();

    float iv0 = b_iah[d], ov0 = b_oah[d];
    float iv1 = iv0,      ov1 = ov0;
    #pragma unroll
    for (int m = 0; m < N_NODE; ++m) {
        const float nim = ni_s[m][d], nom = no_s[m][d];
        iv0 += A_s[n0][m]          * nim;
        iv1 += A_s[n1][m]          * nim;
        ov0 += A_s[n0][N_NODE + m] * nom;
        ov1 += A_s[n1][N_NODE + m] * nom;
    }
    ii_s[n0][d] = iv0; ii_s[n1][d] = iv1;
    io_s[n0][d] = ov0; io_s[n1][d] = ov1;
    __syncthreads();

    float r0 = b_ih[d] + b_hh[d],           r1 = r0;
    float i0 = b_ih[32 + d] + b_hh[32 + d], i1 = i0;
    float gn0 = b_ih[64 + d],               gn1 = gn0;
    float hn0 = b_hh[64 + d],               hn1 = hn0;
    #pragma unroll
    for (int k = 0; k < 32; ++k) {
        const float wri = wih_s[d][k],      wro = wih_s[d][32 + k];
        const float wii = wih_s[32 + d][k], wio = wih_s[32 + d][32 + k];
        const float wni = wih_s[64 + d][k], wno = wih_s[64 + d][32 + k];
        const float whr = whh_s[d][k];
        const float whi = whh_s[32 + d][k];
        const float whn = whh_s[64 + d][k];
        const float a0 = ii_s[n0][k], a1 = ii_s[n1][k];
        const float o0 = io_s[n0][k], o1 = io_s[n1][k];
        const float h0 = h_s[n0][k],  h1 = h_s[n1][k];
        r0  += a0 * wri + o0 * wro + h0 * whr;
        r1  += a1 * wri + o1 * wro + h1 * whr;
        i0  += a0 * wii + o0 * wio + h0 * whi;
        i1  += a1 * wii + o1 * wio + h1 * whi;
        gn0 += a0 * wni + o0 * wno;
        gn1 += a1 * wni + o1 * wno;
        hn0 += h0 * whn;
        hn1 += h1 * whn;
    }

    float hv0, hv1;
    {
        const float rg0 = sigf(r0), ig0 = sigf(i0);
        const float x0  = gn0 + rg0 * hn0;
        const float e0  = __expf(2.0f * fabsf(x0));
        const float ng0 = copysignf(1.0f - 2.0f / (e0 + 1.0f), x0);
        hv0 = ng0 + ig0 * (h_s[n0][d] - ng0);
        const float rg1 = sigf(r1), ig1 = sigf(i1);
        const float x1  = gn1 + rg1 * hn1;
        const float e1  = __expf(2.0f * fabsf(x1));
        const float ng1 = copysignf(1.0f - 2.0f / (e1 + 1.0f), x1);
        hv1 = ng1 + ig1 * (h_s[n1][d] - ng1);
    }
    __syncthreads();
    h_s[n0][d] = hv0;
    h_s[n1][d] = hv1;
    __syncthreads();

    for (int idx = tid; idx < L_SEQ * D_DIM; idx += 256) {
        const int t = idx >> 5, dd = idx & 31;
        const int a = alias_inputs[b * L_SEQ + t];
        const float v = h_s[a][dd];
        if (t < 16) ni_s[t][dd] = v;
        else        no_s[t - 16][dd] = v;
    }
    if (tid == 0) {
        int s = 0;
        for (int t = 0; t < L_SEQ; ++t) s += mask[b * L_SEQ + t];
        last_s = s - 1;
    }
    __syncthreads();

    if (tid < D_DIM) {
        const int lt = last_s;
        const float* sl = (lt < 16) ? &ni_s[lt][0] : &no_s[lt - 16][0];
        float acc = b1[tid];
        #pragma unroll
        for (int k = 0; k < 32; ++k) acc += sl[k] * w1[k * 32 + tid];
        q1_s[tid] = acc;
    }
    __syncthreads();

    for (int idx = tid; idx < L_SEQ * D_DIM; idx += 256) {
        const int t = idx >> 5, dd = idx & 31;
        const float* sp = (t < 16) ? &ni_s[t][0] : &no_s[t - 16][0];
        float q2 = b2[dd];
        #pragma unroll
        for (int k = 0; k < 32; ++k) q2 += sp[k] * w2[k * 32 + dd];
        const float val = sigf(q1_s[dd] + q2) * w3[dd];
        if (t < 16) ii_s[t][dd] = val;
        else        io_s[t - 16][dd] = val;
    }
    __syncthreads();
    if (tid < L_SEQ) {
        const float* tp = (tid < 16) ? &ii_s[tid][0] : &io_s[tid - 16][0];
        float a = 0.0f;
        #pragma unroll
        for (int dd = 0; dd < 32; ++dd) a += tp[dd];
        alpha_s[tid] = a * (float)mask[b * L_SEQ + tid];
    }
    __syncthreads();

    if (tid < D_DIM) {
        float acc = 0.0f;
        #pragma unroll
        for (int t = 0; t < L_SEQ; ++t) {
            const float sv = (t < 16) ? ni_s[t][tid] : no_s[t - 16][tid];
            acc += alpha_s[t] * sv;
        }
        sg_out[b * D_DIM + tid] = acc;
    }
}

// ---------------------------------------------------------------- kernel C1
// emb_b[v][k] = bf16(emb[min(v+1, NV_OUT)][k]), v in [0, EMB_ROWS)
__global__ __launch_bounds__(256) void conv_emb_kernel(
    const float* __restrict__ emb, __hip_bfloat16* __restrict__ emb_b)
{
    const int total = EMB_ROWS * D_DIM;
    for (int i = blockIdx.x * 256 + threadIdx.x; i < total; i += gridDim.x * 256) {
        const int v = i >> 5, k = i & 31;
        int src = v + 1;
        if (src > NV_OUT) src = NV_OUT;     // clamp to last valid emb row
        emb_b[i] = __float2bfloat16(emb[(size_t)src * D_DIM + k]);
    }
}

// ---------------------------------------------------------------- kernel C2
// sg -> hi + lo bf16 split (hi = bf16(x); lo = bf16(x - float(hi)))
__global__ __launch_bounds__(256) void conv_sg_kernel(
    const float* __restrict__ sg,
    __hip_bfloat16* __restrict__ hi, __hip_bfloat16* __restrict__ lo)
{
    const int i = blockIdx.x * 256 + threadIdx.x;   // grid covers 4096*32
    const float x = sg[i];
    const __hip_bfloat16 h = __float2bfloat16(x);
    hi[i] = h;
    lo[i] = __float2bfloat16(x - __bfloat162float(h));
}

// ---------------------------------------------------------------- kernel 2
// scores[b, v] = sum_k sg[b,k] * emb_b[v][k]  via mfma_f32_16x16x32_bf16.
// Wave: 16 b x 64 v (4 MFMA tiles x 2 for hi/lo). Block: 4 waves = 16b x 256v.
// A-frag: lane(rc,kgrp) -> sg[b0+rc][kgrp*8..+8); B-frag: emb_b row (vt+rc)
// slice (contiguous 1KB/wave); D: col=rc, row=kgrp*4+j  [r1==r2 verified].
// Grid: (x = 256 b-tiles [fastest -> emb slice L2-resident], y = 196 v-tiles).
__global__ __launch_bounds__(256) void score6_kernel(
    const __hip_bfloat16* __restrict__ sg_hi,  // [4096,32]
    const __hip_bfloat16* __restrict__ sg_lo,  // [4096,32]
    const __hip_bfloat16* __restrict__ emb_b,  // [EMB_ROWS,32]
    float* __restrict__ out)                   // [4096,49999] f32
{
    const int wave = threadIdx.x >> 6;
    const int lane = threadIdx.x & 63;
    const int rc   = lane & 15;
    const int kgrp = lane >> 4;
    const int b0   = blockIdx.x * 16;
    const int vw   = blockIdx.y * 256 + wave * 64;

    const bf16x8 ah = *reinterpret_cast<const bf16x8*>(
        &sg_hi[(size_t)(b0 + rc) * D_DIM + kgrp * 8]);
    const bf16x8 al = *reinterpret_cast<const bf16x8*>(
        &sg_lo[(size_t)(b0 + rc) * D_DIM + kgrp * 8]);

    #pragma unroll
    for (int s = 0; s < 4; ++s) {
        const int vt = vw + s * 16;
        const bf16x8 bf = *reinterpret_cast<const bf16x8*>(
            &emb_b[(size_t)(vt + rc) * D_DIM + kgrp * 8]);
        f32x4 acc = {0.0f, 0.0f, 0.0f, 0.0f};
        acc = __builtin_amdgcn_mfma_f32_16x16x32_bf16(ah, bf, acc, 0, 0, 0);
        acc = __builtin_amdgcn_mfma_f32_16x16x32_bf16(al, bf, acc, 0, 0, 0);
        const int vcol = vt + rc;
        if (vcol < NV_OUT) {
            #pragma unroll
            for (int j = 0; j < 4; ++j)
                out[(size_t)(b0 + kgrp * 4 + j) * NV_OUT + vcol] = acc[j];
        }
    }
}

// ---------------------------------------------------------------- launch
extern "C" void kernel_launch(void* const* d_in, const int* in_sizes, int n_in,
                              void* d_out, int out_size, void* d_ws, size_t ws_size,
                              hipStream_t stream)
{
    const int*   alias_inputs = (const int*)  d_in[0];
    const float* A      = (const float*)d_in[1];
    const int*   items  = (const int*)  d_in[2];
    const int*   mask   = (const int*)  d_in[3];
    const float* emb    = (const float*)d_in[4];
    const float* w_ih   = (const float*)d_in[5];
    const float* w_hh   = (const float*)d_in[6];
    const float* b_ih   = (const float*)d_in[7];
    const float* b_hh   = (const float*)d_in[8];
    const float* b_iah  = (const float*)d_in[9];
    const float* b_oah  = (const float*)d_in[10];
    const float* w_ein  = (const float*)d_in[11];
    const float* b_ein  = (const float*)d_in[12];
    const float* w_eout = (const float*)d_in[13];
    const float* b_eout = (const float*)d_in[14];
    const float* w1     = (const float*)d_in[15];
    const float* b1     = (const float*)d_in[16];
    const float* w2     = (const float*)d_in[17];
    const float* b2     = (const float*)d_in[18];
    const float* w3     = (const float*)d_in[19];

    float* sg = (float*)d_ws;                                       // 512 KB
    __hip_bfloat16* sg_hi = (__hip_bfloat16*)((char*)d_ws + 512 * 1024);
    __hip_bfloat16* sg_lo = (__hip_bfloat16*)((char*)d_ws + 768 * 1024);
    __hip_bfloat16* emb_b = (__hip_bfloat16*)((char*)d_ws + 1024 * 1024);
    float* out = (float*)d_out;

    hipLaunchKernelGGL(conv_emb_kernel, dim3(2048), dim3(256), 0, stream,
                       emb, emb_b);

    hipLaunchKernelGGL(session3_kernel, dim3(B_BATCH), dim3(256), 0, stream,
                       alias_inputs, A, items, mask, emb,
                       w_ih, w_hh, b_ih, b_hh, b_iah, b_oah,
                       w_ein, b_ein, w_eout, b_eout,
                       w1, b1, w2, b2, w3, sg);

    hipLaunchKernelGGL(conv_sg_kernel, dim3(B_BATCH * D_DIM / 256), dim3(256),
                       0, stream, sg, sg_hi, sg_lo);

    hipLaunchKernelGGL(score6_kernel,
                       dim3(B_BATCH / 16, (NV_OUT + 255) / 256),
                       dim3(256), 0, stream, sg_hi, sg_lo, emb_b, out);
}

// Round 14
// 463.963 us; speedup vs baseline: 1.0003x; 1.0003x over previous
//
#include <hip/hip_runtime.h>
#include <hip/hip_bf16.h>

// SR-GNN session model, MI355X (gfx950). Inputs fp32/int32, output fp32.
// r14: ONE change vs r13 — score grid swapped to x=v-tiles (fastest),
// y=b-tiles. All four score variants (290/281/254/341us) shared b-fastest
// grids -> 4096 concurrent 1KB write stripes at 200KB stride -> HBM write
// locality collapse (~2.5-3 TB/s effective vs fill's 6.6). v-fastest makes
// concurrent blocks write ADJACENT stripes of the SAME 16 rows (16 streams).
// emb_b (3.2MB) fits per-XCD L2 -> re-reads are L2 hits.
// session3 (r10) + conv kernels + MFMA score (r13) otherwise verbatim.
//
// ws: [0) sg f32 512KB | [512K) sg_hi 256KB | [768K) sg_lo 256KB
//     [1M) emb_b bf16 EMB_ROWS x 32 (3.07MB)

#define B_BATCH 4096
#define N_NODE  16
#define L_SEQ   20
#define D_DIM   32
#define NV_OUT  49999
#define EMB_ROWS 50176   // 196*256: last tile reach

typedef float  f32x4  __attribute__((ext_vector_type(4)));
typedef __bf16 bf16x8 __attribute__((ext_vector_type(8)));

__device__ __forceinline__ float sigf(float x) {
    return 1.0f / (1.0f + __expf(-x));
}

// ---------------------------------------------------------------- kernel 1
// VERBATIM r10 session3: one block per session; 8 node-groups x 32 d-lanes.
__global__ __launch_bounds__(256) void session3_kernel(
    const int*   __restrict__ alias_inputs,  // [B,20]
    const float* __restrict__ A,             // [B,16,32]
    const int*   __restrict__ items,         // [B,16]
    const int*   __restrict__ mask,          // [B,20]
    const float* __restrict__ emb,           // [V,32]
    const float* __restrict__ w_ih,          // [96,64]
    const float* __restrict__ w_hh,          // [96,32]
    const float* __restrict__ b_ih, const float* __restrict__ b_hh,
    const float* __restrict__ b_iah, const float* __restrict__ b_oah,
    const float* __restrict__ w_ein, const float* __restrict__ b_ein,
    const float* __restrict__ w_eout, const float* __restrict__ b_eout,
    const float* __restrict__ w1, const float* __restrict__ b1,
    const float* __restrict__ w2, const float* __restrict__ b2,
    const float* __restrict__ w3,
    float* __restrict__ sg_out)              // [B,32] fp32 (ws)
{
    const int b   = blockIdx.x;
    const int tid = threadIdx.x;
    const int g   = tid >> 5;
    const int d   = tid & 31;
    const int n0  = g, n1 = g + 8;

    __shared__ float h_s [N_NODE][D_DIM];
    __shared__ float A_s [N_NODE][2 * N_NODE];
    __shared__ float ni_s[N_NODE][D_DIM];
    __shared__ float no_s[N_NODE][D_DIM];
    __shared__ float ii_s[N_NODE][D_DIM];
    __shared__ float io_s[N_NODE][D_DIM];
    __shared__ float wih_s[96][66];           // bank=(2d+k)%32 -> 2-way (free)
    __shared__ float whh_s[96][34];
    __shared__ float q1_s[D_DIM];
    __shared__ float alpha_s[L_SEQ];
    __shared__ int   last_s;

    for (int idx = tid; idx < 512; idx += 256) {
        const int n = idx >> 5, dd = idx & 31;
        const int it = items[b * N_NODE + n];
        h_s[n][dd] = emb[(size_t)it * D_DIM + dd];
        A_s[n][dd] = A[(size_t)b * 512 + idx];
    }
    for (int f = tid; f < 96 * 64; f += 256) wih_s[f >> 6][f & 63] = w_ih[f];
    for (int f = tid; f < 96 * 32; f += 256) whh_s[f >> 5][f & 31] = w_hh[f];
    __syncthreads();

    float ai0 = b_ein[d], ao0 = b_eout[d];
    float ai1 = ai0,      ao1 = ao0;
    #pragma unroll
    for (int k = 0; k < 32; ++k) {
        const float we = w_ein[k * 32 + d], wo = w_eout[k * 32 + d];
        const float h0 = h_s[n0][k], h1 = h_s[n1][k];
        ai0 += h0 * we; ai1 += h1 * we;
        ao0 += h0 * wo; ao1 += h1 * wo;
    }
    ni_s[n0][d] = ai0; ni_s[n1][d] = ai1;
    no_s[n0][d] = ao0; no_s[n1][d] = ao1;
    __syncthreads();

    float iv0 = b_iah[d], ov0 = b_oah[d];
    float iv1 = iv0,      ov1 = ov0;
    #pragma unroll
    for (int m = 0; m < N_NODE; ++m) {
        const float nim = ni_s[m][d], nom = no_s[m][d];
        iv0 += A_s[n0][m]          * nim;
        iv1 += A_s[n1][m]          * nim;
        ov0 += A_s[n0][N_NODE + m] * nom;
        ov1 += A_s[n1][N_NODE + m] * nom;
    }
    ii_s[n0][d] = iv0; ii_s[n1][d] = iv1;
    io_s[n0][d] = ov0; io_s[n1][d] = ov1;
    __syncthreads();

    float r0 = b_ih[d] + b_hh[d],           r1 = r0;
    float i0 = b_ih[32 + d] + b_hh[32 + d], i1 = i0;
    float gn0 = b_ih[64 + d],               gn1 = gn0;
    float hn0 = b_hh[64 + d],               hn1 = hn0;
    #pragma unroll
    for (int k = 0; k < 32; ++k) {
        const float wri = wih_s[d][k],      wro = wih_s[d][32 + k];
        const float wii = wih_s[32 + d][k], wio = wih_s[32 + d][32 + k];
        const float wni = wih_s[64 + d][k], wno = wih_s[64 + d][32 + k];
        const float whr = whh_s[d][k];
        const float whi = whh_s[32 + d][k];
        const float whn = whh_s[64 + d][k];
        const float a0 = ii_s[n0][k], a1 = ii_s[n1][k];
        const float o0 = io_s[n0][k], o1 = io_s[n1][k];
        const float h0 = h_s[n0][k],  h1 = h_s[n1][k];
        r0  += a0 * wri + o0 * wro + h0 * whr;
        r1  += a1 * wri + o1 * wro + h1 * whr;
        i0  += a0 * wii + o0 * wio + h0 * whi;
        i1  += a1 * wii + o1 * wio + h1 * whi;
        gn0 += a0 * wni + o0 * wno;
        gn1 += a1 * wni + o1 * wno;
        hn0 += h0 * whn;
        hn1 += h1 * whn;
    }

    float hv0, hv1;
    {
        const float rg0 = sigf(r0), ig0 = sigf(i0);
        const float x0  = gn0 + rg0 * hn0;
        const float e0  = __expf(2.0f * fabsf(x0));
        const float ng0 = copysignf(1.0f - 2.0f / (e0 + 1.0f), x0);
        hv0 = ng0 + ig0 * (h_s[n0][d] - ng0);
        const float rg1 = sigf(r1), ig1 = sigf(i1);
        const float x1  = gn1 + rg1 * hn1;
        const float e1  = __expf(2.0f * fabsf(x1));
        const float ng1 = copysignf(1.0f - 2.0f / (e1 + 1.0f), x1);
        hv1 = ng1 + ig1 * (h_s[n1][d] - ng1);
    }
    __syncthreads();
    h_s[n0][d] = hv0;
    h_s[n1][d] = hv1;
    __syncthreads();

    for (int idx = tid; idx < L_SEQ * D_DIM; idx += 256) {
        const int t = idx >> 5, dd = idx & 31;
        const int a = alias_inputs[b * L_SEQ + t];
        const float v = h_s[a][dd];
        if (t < 16) ni_s[t][dd] = v;
        else        no_s[t - 16][dd] = v;
    }
    if (tid == 0) {
        int s = 0;
        for (int t = 0; t < L_SEQ; ++t) s += mask[b * L_SEQ + t];
        last_s = s - 1;
    }
    __syncthreads();

    if (tid < D_DIM) {
        const int lt = last_s;
        const float* sl = (lt < 16) ? &ni_s[lt][0] : &no_s[lt - 16][0];
        float acc = b1[tid];
        #pragma unroll
        for (int k = 0; k < 32; ++k) acc += sl[k] * w1[k * 32 + tid];
        q1_s[tid] = acc;
    }
    __syncthreads();

    for (int idx = tid; idx < L_SEQ * D_DIM; idx += 256) {
        const int t = idx >> 5, dd = idx & 31;
        const float* sp = (t < 16) ? &ni_s[t][0] : &no_s[t - 16][0];
        float q2 = b2[dd];
        #pragma unroll
        for (int k = 0; k < 32; ++k) q2 += sp[k] * w2[k * 32 + dd];
        const float val = sigf(q1_s[dd] + q2) * w3[dd];
        if (t < 16) ii_s[t][dd] = val;
        else        io_s[t - 16][dd] = val;
    }
    __syncthreads();
    if (tid < L_SEQ) {
        const float* tp = (tid < 16) ? &ii_s[tid][0] : &io_s[tid - 16][0];
        float a = 0.0f;
        #pragma unroll
        for (int dd = 0; dd < 32; ++dd) a += tp[dd];
        alpha_s[tid] = a * (float)mask[b * L_SEQ + tid];
    }
    __syncthreads();

    if (tid < D_DIM) {
        float acc = 0.0f;
        #pragma unroll
        for (int t = 0; t < L_SEQ; ++t) {
            const float sv = (t < 16) ? ni_s[t][tid] : no_s[t - 16][tid];
            acc += alpha_s[t] * sv;
        }
        sg_out[b * D_DIM + tid] = acc;
    }
}

// ---------------------------------------------------------------- kernel C1
__global__ __launch_bounds__(256) void conv_emb_kernel(
    const float* __restrict__ emb, __hip_bfloat16* __restrict__ emb_b)
{
    const int total = EMB_ROWS * D_DIM;
    for (int i = blockIdx.x * 256 + threadIdx.x; i < total; i += gridDim.x * 256) {
        const int v = i >> 5, k = i & 31;
        int src = v + 1;
        if (src > NV_OUT) src = NV_OUT;
        emb_b[i] = __float2bfloat16(emb[(size_t)src * D_DIM + k]);
    }
}

// ---------------------------------------------------------------- kernel C2
__global__ __launch_bounds__(256) void conv_sg_kernel(
    const float* __restrict__ sg,
    __hip_bfloat16* __restrict__ hi, __hip_bfloat16* __restrict__ lo)
{
    const int i = blockIdx.x * 256 + threadIdx.x;
    const float x = sg[i];
    const __hip_bfloat16 h = __float2bfloat16(x);
    hi[i] = h;
    lo[i] = __float2bfloat16(x - __bfloat162float(h));
}

// ---------------------------------------------------------------- kernel 2
// score7: MFMA score (r13's score6) with v-fastest grid.
// Grid: (x = 196 v-tiles [fastest -> concurrent blocks write adjacent
//        stripes of the SAME 16 rows], y = 256 b-tiles).
__global__ __launch_bounds__(256) void score7_kernel(
    const __hip_bfloat16* __restrict__ sg_hi,  // [4096,32]
    const __hip_bfloat16* __restrict__ sg_lo,  // [4096,32]
    const __hip_bfloat16* __restrict__ emb_b,  // [EMB_ROWS,32]
    float* __restrict__ out)                   // [4096,49999] f32
{
    const int wave = threadIdx.x >> 6;
    const int lane = threadIdx.x & 63;
    const int rc   = lane & 15;
    const int kgrp = lane >> 4;
    const int b0   = blockIdx.y * 16;
    const int vw   = blockIdx.x * 256 + wave * 64;

    const bf16x8 ah = *reinterpret_cast<const bf16x8*>(
        &sg_hi[(size_t)(b0 + rc) * D_DIM + kgrp * 8]);
    const bf16x8 al = *reinterpret_cast<const bf16x8*>(
        &sg_lo[(size_t)(b0 + rc) * D_DIM + kgrp * 8]);

    #pragma unroll
    for (int s = 0; s < 4; ++s) {
        const int vt = vw + s * 16;
        const bf16x8 bf = *reinterpret_cast<const bf16x8*>(
            &emb_b[(size_t)(vt + rc) * D_DIM + kgrp * 8]);
        f32x4 acc = {0.0f, 0.0f, 0.0f, 0.0f};
        acc = __builtin_amdgcn_mfma_f32_16x16x32_bf16(ah, bf, acc, 0, 0, 0);
        acc = __builtin_amdgcn_mfma_f32_16x16x32_bf16(al, bf, acc, 0, 0, 0);
        const int vcol = vt + rc;
        if (vcol < NV_OUT) {
            #pragma unroll
            for (int j = 0; j < 4; ++j)
                out[(size_t)(b0 + kgrp * 4 + j) * NV_OUT + vcol] = acc[j];
        }
    }
}

// ---------------------------------------------------------------- launch
extern "C" void kernel_launch(void* const* d_in, const int* in_sizes, int n_in,
                              void* d_out, int out_size, void* d_ws, size_t ws_size,
                              hipStream_t stream)
{
    const int*   alias_inputs = (const int*)  d_in[0];
    const float* A      = (const float*)d_in[1];
    const int*   items  = (const int*)  d_in[2];
    const int*   mask   = (const int*)  d_in[3];
    const float* emb    = (const float*)d_in[4];
    const float* w_ih   = (const float*)d_in[5];
    const float* w_hh   = (const float*)d_in[6];
    const float* b_ih   = (const float*)d_in[7];
    const float* b_hh   = (const float*)d_in[8];
    const float* b_iah  = (const float*)d_in[9];
    const float* b_oah  = (const float*)d_in[10];
    const float* w_ein  = (const float*)d_in[11];
    const float* b_ein  = (const float*)d_in[12];
    const float* w_eout = (const float*)d_in[13];
    const float* b_eout = (const float*)d_in[14];
    const float* w1     = (const float*)d_in[15];
    const float* b1     = (const float*)d_in[16];
    const float* w2     = (const float*)d_in[17];
    const float* b2     = (const float*)d_in[18];
    const float* w3     = (const float*)d_in[19];

    float* sg = (float*)d_ws;                                       // 512 KB
    __hip_bfloat16* sg_hi = (__hip_bfloat16*)((char*)d_ws + 512 * 1024);
    __hip_bfloat16* sg_lo = (__hip_bfloat16*)((char*)d_ws + 768 * 1024);
    __hip_bfloat16* emb_b = (__hip_bfloat16*)((char*)d_ws + 1024 * 1024);
    float* out = (float*)d_out;

    hipLaunchKernelGGL(conv_emb_kernel, dim3(2048), dim3(256), 0, stream,
                       emb, emb_b);

    hipLaunchKernelGGL(session3_kernel, dim3(B_BATCH), dim3(256), 0, stream,
                       alias_inputs, A, items, mask, emb,
                       w_ih, w_hh, b_ih, b_hh, b_iah, b_oah,
                       w_ein, b_ein, w_eout, b_eout,
                       w1, b1, w2, b2, w3, sg);

    hipLaunchKernelGGL(conv_sg_kernel, dim3(B_BATCH * D_DIM / 256), dim3(256),
                       0, stream, sg, sg_hi, sg_lo);

    hipLaunchKernelGGL(score7_kernel,
                       dim3((NV_OUT + 255) / 256, B_BATCH / 16),
                       dim3(256), 0, stream, sg_hi, sg_lo, emb_b, out);
}

// Round 15
// 316.570 us; speedup vs baseline: 1.4661x; 1.4656x over previous
//
#include <hip/hip_runtime.h>
#include <hip/hip_bf16.h>

// SR-GNN session model, MI355X (gfx950). Inputs fp32/int32, output fp32.
// r15: MFMA score keeps r13 math but stages the 16x256 f32 output tile in
// LDS (stride 260 -> 2-way write aliasing, free) and stores CONTIGUOUS 1KB
// dwordx4 nontemporal runs per wave-inst. r13/r14's direct D-fragment stores
// emitted 4x64B segments per inst (partial 128B lines -> ~2x write cost,
// orientation-invariant = r14's null result). Fill calibrates streaming
// contiguous writes at 6.7 TB/s.
// session3 (r10) + conv kernels verbatim.
//
// ws: [0) sg f32 512KB | [512K) sg_hi 256KB | [768K) sg_lo 256KB
//     [1M) emb_b bf16 EMB_ROWS x 32 (3.07MB)

#define B_BATCH 4096
#define N_NODE  16
#define L_SEQ   20
#define D_DIM   32
#define NV_OUT  49999
#define EMB_ROWS 50176   // 196*256: last tile reach

typedef float  f32x4  __attribute__((ext_vector_type(4)));
typedef float  f32x4u __attribute__((ext_vector_type(4), aligned(4)));
typedef __bf16 bf16x8 __attribute__((ext_vector_type(8)));

__device__ __forceinline__ float sigf(float x) {
    return 1.0f / (1.0f + __expf(-x));
}

// ---------------------------------------------------------------- kernel 1
// VERBATIM r10 session3: one block per session; 8 node-groups x 32 d-lanes.
__global__ __launch_bounds__(256) void session3_kernel(
    const int*   __restrict__ alias_inputs,  // [B,20]
    const float* __restrict__ A,             // [B,16,32]
    const int*   __restrict__ items,         // [B,16]
    const int*   __restrict__ mask,          // [B,20]
    const float* __restrict__ emb,           // [V,32]
    const float* __restrict__ w_ih,          // [96,64]
    const float* __restrict__ w_hh,          // [96,32]
    const float* __restrict__ b_ih, const float* __restrict__ b_hh,
    const float* __restrict__ b_iah, const float* __restrict__ b_oah,
    const float* __restrict__ w_ein, const float* __restrict__ b_ein,
    const float* __restrict__ w_eout, const float* __restrict__ b_eout,
    const float* __restrict__ w1, const float* __restrict__ b1,
    const float* __restrict__ w2, const float* __restrict__ b2,
    const float* __restrict__ w3,
    float* __restrict__ sg_out)              // [B,32] fp32 (ws)
{
    const int b   = blockIdx.x;
    const int tid = threadIdx.x;
    const int g   = tid >> 5;
    const int d   = tid & 31;
    const int n0  = g, n1 = g + 8;

    __shared__ float h_s [N_NODE][D_DIM];
    __shared__ float A_s [N_NODE][2 * N_NODE];
    __shared__ float ni_s[N_NODE][D_DIM];
    __shared__ float no_s[N_NODE][D_DIM];
    __shared__ float ii_s[N_NODE][D_DIM];
    __shared__ float io_s[N_NODE][D_DIM];
    __shared__ float wih_s[96][66];           // bank=(2d+k)%32 -> 2-way (free)
    __shared__ float whh_s[96][34];
    __shared__ float q1_s[D_DIM];
    __shared__ float alpha_s[L_SEQ];
    __shared__ int   last_s;

    for (int idx = tid; idx < 512; idx += 256) {
        const int n = idx >> 5, dd = idx & 31;
        const int it = items[b * N_NODE + n];
        h_s[n][dd] = emb[(size_t)it * D_DIM + dd];
        A_s[n][dd] = A[(size_t)b * 512 + idx];
    }
    for (int f = tid; f < 96 * 64; f += 256) wih_s[f >> 6][f & 63] = w_ih[f];
    for (int f = tid; f < 96 * 32; f += 256) whh_s[f >> 5][f & 31] = w_hh[f];
    __syncthreads();

    float ai0 = b_ein[d], ao0 = b_eout[d];
    float ai1 = ai0,      ao1 = ao0;
    #pragma unroll
    for (int k = 0; k < 32; ++k) {
        const float we = w_ein[k * 32 + d], wo = w_eout[k * 32 + d];
        const float h0 = h_s[n0][k], h1 = h_s[n1][k];
        ai0 += h0 * we; ai1 += h1 * we;
        ao0 += h0 * wo; ao1 += h1 * wo;
    }
    ni_s[n0][d] = ai0; ni_s[n1][d] = ai1;
    no_s[n0][d] = ao0; no_s[n1][d] = ao1;
    __syncthreads();

    float iv0 = b_iah[d], ov0 = b_oah[d];
    float iv1 = iv0,      ov1 = ov0;
    #pragma unroll
    for (int m = 0; m < N_NODE; ++m) {
        const float nim = ni_s[m][d], nom = no_s[m][d];
        iv0 += A_s[n0][m]          * nim;
        iv1 += A_s[n1][m]          * nim;
        ov0 += A_s[n0][N_NODE + m] * nom;
        ov1 += A_s[n1][N_NODE + m] * nom;
    }
    ii_s[n0][d] = iv0; ii_s[n1][d] = iv1;
    io_s[n0][d] = ov0; io_s[n1][d] = ov1;
    __syncthreads();

    float r0 = b_ih[d] + b_hh[d],           r1 = r0;
    float i0 = b_ih[32 + d] + b_hh[32 + d], i1 = i0;
    float gn0 = b_ih[64 + d],               gn1 = gn0;
    float hn0 = b_hh[64 + d],               hn1 = hn0;
    #pragma unroll
    for (int k = 0; k < 32; ++k) {
        const float wri = wih_s[d][k],      wro = wih_s[d][32 + k];
        const float wii = wih_s[32 + d][k], wio = wih_s[32 + d][32 + k];
        const float wni = wih_s[64 + d][k], wno = wih_s[64 + d][32 + k];
        const float whr = whh_s[d][k];
        const float whi = whh_s[32 + d][k];
        const float whn = whh_s[64 + d][k];
        const float a0 = ii_s[n0][k], a1 = ii_s[n1][k];
        const float o0 = io_s[n0][k], o1 = io_s[n1][k];
        const float h0 = h_s[n0][k],  h1 = h_s[n1][k];
        r0  += a0 * wri + o0 * wro + h0 * whr;
        r1  += a1 * wri + o1 * wro + h1 * whr;
        i0  += a0 * wii + o0 * wio + h0 * whi;
        i1  += a1 * wii + o1 * wio + h1 * whi;
        gn0 += a0 * wni + o0 * wno;
        gn1 += a1 * wni + o1 * wno;
        hn0 += h0 * whn;
        hn1 += h1 * whn;
    }

    float hv0, hv1;
    {
        const float rg0 = sigf(r0), ig0 = sigf(i0);
        const float x0  = gn0 + rg0 * hn0;
        const float e0  = __expf(2.0f * fabsf(x0));
        const float ng0 = copysignf(1.0f - 2.0f / (e0 + 1.0f), x0);
        hv0 = ng0 + ig0 * (h_s[n0][d] - ng0);
        const float rg1 = sigf(r1), ig1 = sigf(i1);
        const float x1  = gn1 + rg1 * hn1;
        const float e1  = __expf(2.0f * fabsf(x1));
        const float ng1 = copysignf(1.0f - 2.0f / (e1 + 1.0f), x1);
        hv1 = ng1 + ig1 * (h_s[n1][d] - ng1);
    }
    __syncthreads();
    h_s[n0][d] = hv0;
    h_s[n1][d] = hv1;
    __syncthreads();

    for (int idx = tid; idx < L_SEQ * D_DIM; idx += 256) {
        const int t = idx >> 5, dd = idx & 31;
        const int a = alias_inputs[b * L_SEQ + t];
        const float v = h_s[a][dd];
        if (t < 16) ni_s[t][dd] = v;
        else        no_s[t - 16][dd] = v;
    }
    if (tid == 0) {
        int s = 0;
        for (int t = 0; t < L_SEQ; ++t) s += mask[b * L_SEQ + t];
        last_s = s - 1;
    }
    __syncthreads();

    if (tid < D_DIM) {
        const int lt = last_s;
        const float* sl = (lt < 16) ? &ni_s[lt][0] : &no_s[lt - 16][0];
        float acc = b1[tid];
        #pragma unroll
        for (int k = 0; k < 32; ++k) acc += sl[k] * w1[k * 32 + tid];
        q1_s[tid] = acc;
    }
    __syncthreads();

    for (int idx = tid; idx < L_SEQ * D_DIM; idx += 256) {
        const int t = idx >> 5, dd = idx & 31;
        const float* sp = (t < 16) ? &ni_s[t][0] : &no_s[t - 16][0];
        float q2 = b2[dd];
        #pragma unroll
        for (int k = 0; k < 32; ++k) q2 += sp[k] * w2[k * 32 + dd];
        const float val = sigf(q1_s[dd] + q2) * w3[dd];
        if (t < 16) ii_s[t][dd] = val;
        else        io_s[t - 16][dd] = val;
    }
    __syncthreads();
    if (tid < L_SEQ) {
        const float* tp = (tid < 16) ? &ii_s[tid][0] : &io_s[tid - 16][0];
        float a = 0.0f;
        #pragma unroll
        for (int dd = 0; dd < 32; ++dd) a += tp[dd];
        alpha_s[tid] = a * (float)mask[b * L_SEQ + tid];
    }
    __syncthreads();

    if (tid < D_DIM) {
        float acc = 0.0f;
        #pragma unroll
        for (int t = 0; t < L_SEQ; ++t) {
            const float sv = (t < 16) ? ni_s[t][tid] : no_s[t - 16][tid];
            acc += alpha_s[t] * sv;
        }
        sg_out[b * D_DIM + tid] = acc;
    }
}

// ---------------------------------------------------------------- kernel C1
__global__ __launch_bounds__(256) void conv_emb_kernel(
    const float* __restrict__ emb, __hip_bfloat16* __restrict__ emb_b)
{
    const int total = EMB_ROWS * D_DIM;
    for (int i = blockIdx.x * 256 + threadIdx.x; i < total; i += gridDim.x * 256) {
        const int v = i >> 5, k = i & 31;
        int src = v + 1;
        if (src > NV_OUT) src = NV_OUT;
        emb_b[i] = __float2bfloat16(emb[(size_t)src * D_DIM + k]);
    }
}

// ---------------------------------------------------------------- kernel C2
__global__ __launch_bounds__(256) void conv_sg_kernel(
    const float* __restrict__ sg,
    __hip_bfloat16* __restrict__ hi, __hip_bfloat16* __restrict__ lo)
{
    const int i = blockIdx.x * 256 + threadIdx.x;
    const float x = sg[i];
    const __hip_bfloat16 h = __float2bfloat16(x);
    hi[i] = h;
    lo[i] = __float2bfloat16(x - __bfloat162float(h));
}

// ---------------------------------------------------------------- kernel 2
// score8: r13 MFMA math; output tile staged in LDS then stored as contiguous
// 1KB dwordx4 nontemporal runs (wave w stores rows 4w..4w+3).
// LDS stride 260 floats: write phase bank=(16*kgrp+4j+16s+rc)%32 -> exactly
// 2 lanes/bank (free, m136). Grid: (x = 196 v-tiles, y = 256 b-tiles).
__global__ __launch_bounds__(256) void score8_kernel(
    const __hip_bfloat16* __restrict__ sg_hi,  // [4096,32]
    const __hip_bfloat16* __restrict__ sg_lo,  // [4096,32]
    const __hip_bfloat16* __restrict__ emb_b,  // [EMB_ROWS,32]
    float* __restrict__ out)                   // [4096,49999] f32
{
    __shared__ float T[16][260];               // 16.6 KB
    const int wave = threadIdx.x >> 6;
    const int lane = threadIdx.x & 63;
    const int rc   = lane & 15;
    const int kgrp = lane >> 4;
    const int b0   = blockIdx.y * 16;
    const int v0   = blockIdx.x * 256;
    const int vw   = v0 + wave * 64;

    const bf16x8 ah = *reinterpret_cast<const bf16x8*>(
        &sg_hi[(size_t)(b0 + rc) * D_DIM + kgrp * 8]);
    const bf16x8 al = *reinterpret_cast<const bf16x8*>(
        &sg_lo[(size_t)(b0 + rc) * D_DIM + kgrp * 8]);

    #pragma unroll
    for (int s = 0; s < 4; ++s) {
        const int vt = vw + s * 16;
        const bf16x8 bf = *reinterpret_cast<const bf16x8*>(
            &emb_b[(size_t)(vt + rc) * D_DIM + kgrp * 8]);
        f32x4 acc = {0.0f, 0.0f, 0.0f, 0.0f};
        acc = __builtin_amdgcn_mfma_f32_16x16x32_bf16(ah, bf, acc, 0, 0, 0);
        acc = __builtin_amdgcn_mfma_f32_16x16x32_bf16(al, bf, acc, 0, 0, 0);
        const int col = wave * 64 + s * 16 + rc;   // col within tile
        #pragma unroll
        for (int j = 0; j < 4; ++j)
            T[kgrp * 4 + j][col] = acc[j];
    }
    __syncthreads();

    // wave w stores rows 4w..4w+3: 1KB contiguous dwordx4 per inst
    if (v0 + 256 <= NV_OUT) {
        #pragma unroll
        for (int r = 0; r < 4; ++r) {
            const int row = wave * 4 + r;
            const f32x4 val = *reinterpret_cast<const f32x4*>(&T[row][lane * 4]);
            f32x4u* op = reinterpret_cast<f32x4u*>(
                &out[(size_t)(b0 + row) * NV_OUT + v0 + lane * 4]);
            __builtin_nontemporal_store(val, op);
        }
    } else {
        // partial last v-tile (1 of 196): masked scalar stores
        #pragma unroll
        for (int r = 0; r < 4; ++r) {
            const int row = wave * 4 + r;
            float* op = &out[(size_t)(b0 + row) * NV_OUT];
            #pragma unroll
            for (int j = 0; j < 4; ++j) {
                const int c = lane * 4 + j;
                if (v0 + c < NV_OUT) op[v0 + c] = T[row][c];
            }
        }
    }
}

// ---------------------------------------------------------------- launch
extern "C" void kernel_launch(void* const* d_in, const int* in_sizes, int n_in,
                              void* d_out, int out_size, void* d_ws, size_t ws_size,
                              hipStream_t stream)
{
    const int*   alias_inputs = (const int*)  d_in[0];
    const float* A      = (const float*)d_in[1];
    const int*   items  = (const int*)  d_in[2];
    const int*   mask   = (const int*)  d_in[3];
    const float* emb    = (const float*)d_in[4];
    const float* w_ih   = (const float*)d_in[5];
    const float* w_hh   = (const float*)d_in[6];
    const float* b_ih   = (const float*)d_in[7];
    const float* b_hh   = (const float*)d_in[8];
    const float* b_iah  = (const float*)d_in[9];
    const float* b_oah  = (const float*)d_in[10];
    const float* w_ein  = (const float*)d_in[11];
    const float* b_ein  = (const float*)d_in[12];
    const float* w_eout = (const float*)d_in[13];
    const float* b_eout = (const float*)d_in[14];
    const float* w1     = (const float*)d_in[15];
    const float* b1     = (const float*)d_in[16];
    const float* w2     = (const float*)d_in[17];
    const float* b2     = (const float*)d_in[18];
    const float* w3     = (const float*)d_in[19];

    float* sg = (float*)d_ws;                                       // 512 KB
    __hip_bfloat16* sg_hi = (__hip_bfloat16*)((char*)d_ws + 512 * 1024);
    __hip_bfloat16* sg_lo = (__hip_bfloat16*)((char*)d_ws + 768 * 1024);
    __hip_bfloat16* emb_b = (__hip_bfloat16*)((char*)d_ws + 1024 * 1024);
    float* out = (float*)d_out;

    hipLaunchKernelGGL(conv_emb_kernel, dim3(2048), dim3(256), 0, stream,
                       emb, emb_b);

    hipLaunchKernelGGL(session3_kernel, dim3(B_BATCH), dim3(256), 0, stream,
                       alias_inputs, A, items, mask, emb,
                       w_ih, w_hh, b_ih, b_hh, b_iah, b_oah,
                       w_ein, b_ein, w_eout, b_eout,
                       w1, b1, w2, b2, w3, sg);

    hipLaunchKernelGGL(conv_sg_kernel, dim3(B_BATCH * D_DIM / 256), dim3(256),
                       0, stream, sg, sg_hi, sg_lo);

    hipLaunchKernelGGL(score8_kernel,
                       dim3((NV_OUT + 255) / 256, B_BATCH / 16),
                       dim3(256), 0, stream, sg_hi, sg_lo, emb_b, out);
}